// Round 1
// baseline (482.893 us; speedup 1.0000x reference)
//
#include <hip/hip_runtime.h>

// score[i] = dot(x[src[i]], W[0:512]) + dot(x[dst[i]], W[512:1024])
//          + dot(e[i],      W[1024:1536]) + b
// Factored: precompute per-node s[n]=x[n].W1, t[n]=x[n].W2 (reads x ONCE),
// then per-edge gather of two scalars + one coalesced e-row dot.
// Memory-bound: ~432 MB compulsory traffic -> ~69 us at 6.3 TB/s.

constexpr int D = 512;

__device__ __forceinline__ float dot4(const float4 a, const float4 b) {
    return a.x * b.x + a.y * b.y + a.z * b.z + a.w * b.w;
}

// One wave (64 lanes) per node. Lane l covers elements [l*4, l*4+4) and
// [256 + l*4, 256+l*4+4) of the 512-wide row -> each float4 load instruction
// is a fully coalesced contiguous 1 KB wave access.
__global__ __launch_bounds__(256) void node_scores_kernel(
    const float* __restrict__ x, const float* __restrict__ W,
    float* __restrict__ s_out, float* __restrict__ t_out, int n_nodes)
{
    const int lane    = threadIdx.x & 63;
    const int wave    = (blockIdx.x * blockDim.x + threadIdx.x) >> 6;
    const int n_waves = (gridDim.x * blockDim.x) >> 6;

    const float4* W4 = (const float4*)W;
    // W1 = W[0:512), W2 = W[512:1024) — held in registers across the loop.
    const float4 w1a = W4[lane];
    const float4 w1b = W4[64 + lane];
    const float4 w2a = W4[128 + lane];
    const float4 w2b = W4[192 + lane];

    for (int n = wave; n < n_nodes; n += n_waves) {
        const float4* xr = (const float4*)(x + (size_t)n * D);
        const float4 xa = xr[lane];
        const float4 xb = xr[64 + lane];
        float s = dot4(xa, w1a) + dot4(xb, w1b);
        float t = dot4(xa, w2a) + dot4(xb, w2b);
#pragma unroll
        for (int off = 32; off > 0; off >>= 1) {
            s += __shfl_xor(s, off, 64);
            t += __shfl_xor(t, off, 64);
        }
        if (lane == 0) {
            s_out[n] = s;
            t_out[n] = t;
        }
    }
}

// One wave per edge. W3 fragment lives in registers for ~20 edges/wave.
// Index + node-score gathers are issued by all lanes (same-address broadcast,
// single cache line) BEFORE the row dot so their latency hides under the
// 2 KB e-row fetch.
__global__ __launch_bounds__(256) void edge_scores_kernel(
    const float* __restrict__ e, const int* __restrict__ src,
    const int* __restrict__ dst, const float* __restrict__ W,
    const float* __restrict__ bp, const float* __restrict__ s_in,
    const float* __restrict__ t_in, float* __restrict__ out, int n_edges)
{
    const int lane    = threadIdx.x & 63;
    const int wave    = (blockIdx.x * blockDim.x + threadIdx.x) >> 6;
    const int n_waves = (gridDim.x * blockDim.x) >> 6;

    const float4* W4 = (const float4*)W;
    // W3 = W[1024:1536)
    const float4 w3a = W4[256 + lane];
    const float4 w3b = W4[320 + lane];
    const float bias = bp[0];

    for (int i = wave; i < n_edges; i += n_waves) {
        const int   si = src[i];
        const int   di = dst[i];
        const float sv = s_in[si];
        const float tv = t_in[di];

        const float4* er = (const float4*)(e + (size_t)i * D);
        const float4 ea = er[lane];
        const float4 eb = er[64 + lane];
        float p = dot4(ea, w3a) + dot4(eb, w3b);
#pragma unroll
        for (int off = 32; off > 0; off >>= 1) p += __shfl_xor(p, off, 64);

        if (lane == 0) out[i] = p + sv + tv + bias;
    }
}

extern "C" void kernel_launch(void* const* d_in, const int* in_sizes, int n_in,
                              void* d_out, int out_size, void* d_ws, size_t ws_size,
                              hipStream_t stream) {
    const float* x   = (const float*)d_in[0];
    const float* e   = (const float*)d_in[1];
    const int*   src = (const int*)d_in[2];
    const int*   dst = (const int*)d_in[3];
    const float* W   = (const float*)d_in[4];
    const float* b   = (const float*)d_in[5];

    const int n_nodes = in_sizes[0] / D;   // 50000
    const int n_edges = in_sizes[2];       // 160000

    float* s = (float*)d_ws;               // [n_nodes]
    float* t = s + n_nodes;                // [n_nodes]
    float* out = (float*)d_out;            // [n_edges]

    // 1024 blocks * 4 waves = 4096 waves over 50000 nodes (~12 nodes/wave).
    node_scores_kernel<<<1024, 256, 0, stream>>>(x, W, s, t, n_nodes);
    // 2048 blocks * 4 waves = 8192 waves over 160000 edges (~20 edges/wave).
    edge_scores_kernel<<<2048, 256, 0, stream>>>(e, src, dst, W, b, s, t, out, n_edges);
}